// Round 16
// baseline (226.843 us; speedup 1.0000x reference)
//
#include <hip/hip_runtime.h>
#include <hip/hip_bf16.h>
#include <stdint.h>

#define BB 2
#define LLEN 1024
#define MM 25
#define KK 32

// d_out is FLOAT32, concatenated in return order:
// (V, E, E_idx, Y_nodes, Y_edges, Y_m) — offsets in f32 elements.
#define OFF_V   0
#define OFF_E   6553600
#define OFF_EI  14942208
#define OFF_YN  15007744
#define OFF_YE  21561344
#define OFF_YM  185401344

#define KP 424          // edge A-tile row stride (bf16)
#define KP2 168         // node A-tile row stride (bf16)
#define NR 5            // rows per nodes block

// phase-1 virtual blocks: [0,512) topk | [512,550) prep | [550,13350) ynodes
#define P1_PREP 512
#define P1_YN   550
#define P1_END  (P1_YN + BB*LLEN*MM/4)   // 13350
// phase-2 virtual blocks: [0,2048) yedges | [2048,4096) edges(32/blk) | [4096,4506) nodes
#define NB_YE  (BB*LLEN)                      // 2048
#define VB_E   NB_YE
#define NB_E   (BB*LLEN)                      // 2048 (one residue-row each)
#define VB_N   (VB_E + NB_E)                  // 4096
#define VB_END (VB_N + (BB*LLEN+NR-1)/NR)     // 4506
#define NB_OTH (VB_END - NB_YE)               // 2458
#define INTERL (2*NB_YE)                      // 4096: 1:1 ye/oth pairs

#define SCRATCH_BYTES (680*1024)

typedef __attribute__((ext_vector_type(8))) short short8_t;
typedef __attribute__((ext_vector_type(4))) float f32x4;

__constant__ int g_PA[24] = {0,2,3,4,1,1,1,1,0,0,0,4,4,3,0,2,3,4,2,3,4,2,3,2};
__constant__ int g_PB[24] = {0,2,3,4,0,2,3,4,2,3,4,2,3,2,1,1,1,1,0,0,0,4,4,3};

__device__ __forceinline__ float rbf_val(float d, int r) {
    float mu = 2.0f + (20.0f / 15.0f) * (float)r;
    float z = (d - mu) * 0.8f;
    return __expf(-z * z);
}

// ------------------------------------------------- phase 1: topk + prep + ynodes
__global__ __launch_bounds__(256) void k_phase1(
    int vbase,
    const float* __restrict__ X, const float* __restrict__ mask,
    const float* __restrict__ W, const float* __restrict__ yeW,
    const float* __restrict__ npdW,
    __hip_bfloat16* __restrict__ Bp, __hip_bfloat16* __restrict__ Bp2,
    __hip_bfloat16* __restrict__ Bp3,
    int* __restrict__ eidx, float* __restrict__ dnb,
    float* __restrict__ outEI,
    const int* __restrict__ Yt, const float* __restrict__ Ym,
    const int* __restrict__ ptab, const float* __restrict__ ynW,
    const float* __restrict__ lnYNg, const float* __restrict__ lnYNb,
    float* __restrict__ outYN, float* __restrict__ outYM)
{
    __shared__ float sx[1024], syy[1024], sz[1024], smk[1024];
    int vb = blockIdx.x + vbase;
    int tid = threadIdx.x;
    int wid = tid >> 6, lane = tid & 63;

    if (vb >= P1_YN) {                    // ---- ynodes (light, input-only deps)
        int row = (vb - P1_YN) * 4 + wid;
        int t = Yt[row];
        int p1 = ptab[120 + t], p2 = ptab[240 + t];
        int r0 = t, r1 = 120 + p1, r2 = 139 + p2;
        float x0 = ynW[r0*128 + lane] + ynW[r1*128 + lane] + ynW[r2*128 + lane];
        float x1 = ynW[r0*128 + 64 + lane] + ynW[r1*128 + 64 + lane] + ynW[r2*128 + 64 + lane];
        float s = x0 + x1, s2 = x0*x0 + x1*x1;
        #pragma unroll
        for (int o = 1; o < 64; o <<= 1) { s += __shfl_xor(s, o); s2 += __shfl_xor(s2, o); }
        float mean = s * (1.0f/128.0f);
        float var  = s2 * (1.0f/128.0f) - mean*mean;
        float inv  = rsqrtf(var + 1e-5f);
        size_t base = (size_t)row * 128;
        outYN[base + lane]      = (x0 - mean)*inv*lnYNg[lane]    + lnYNb[lane];
        outYN[base + 64 + lane] = (x1 - mean)*inv*lnYNg[64+lane] + lnYNb[64+lane];
        if (lane == 0) outYM[row] = Ym[row];
        return;
    }

    if (vb >= P1_PREP) {                  // ---- B-pack prep
        int idx = (vb - P1_PREP) * 256 + tid;
        if (idx < 6656) {
            int ln = idx & 63, tt = (idx >> 6) & 7, ks = idx >> 9;
            int k0 = ks*32 + (ln >> 4)*8;
            int n  = tt*16 + (ln & 15);
            __hip_bfloat16* dst = Bp + (size_t)idx * 8;
            #pragma unroll
            for (int j = 0; j < 8; ++j) dst[j] = __float2bfloat16(W[(size_t)(k0 + j)*128 + n]);
        } else if (idx < 7168) {
            int i2 = idx - 6656;
            int ln = i2 & 63, tt = i2 >> 6;
            int kg = ln >> 4;
            int n  = tt*16 + (ln & 15);
            __hip_bfloat16* dst = Bp2 + (size_t)i2 * 8;
            #pragma unroll
            for (int j = 0; j < 8; ++j) {
                float v = (kg < 2) ? yeW[(size_t)(kg*8 + j)*128 + n] : 0.0f;
                dst[j] = __float2bfloat16(v);
            }
        } else if (idx < 9728) {
            int i3 = idx - 7168;
            int ln = i3 & 63, tt = (i3 >> 6) & 7, ks = i3 >> 9;
            int k0 = ks*32 + (ln >> 4)*8;
            int n  = tt*16 + (ln & 15);
            __hip_bfloat16* dst = Bp3 + (size_t)i3 * 8;
            #pragma unroll
            for (int j = 0; j < 8; ++j) {
                int k = k0 + j;
                float v = (k < 148) ? npdW[(size_t)k*128 + n] : 0.0f;
                dst[j] = __float2bfloat16(v);
            }
        }
        return;
    }

    // ---- top-k (validated wave tournament, LDS-staged coords)
    int row0 = vb * 4;
    int b = row0 >> 10;
    const float* Xb = X + (size_t)b * LLEN * 12;
    const float* mb = mask + b * LLEN;
    for (int j = tid; j < 1024; j += 256) {
        sx[j]  = Xb[j*12+3];
        syy[j] = Xb[j*12+4];
        sz[j]  = Xb[j*12+5];
        smk[j] = mb[j];
    }
    __syncthreads();

    int row = row0 + wid, i = row & 1023;
    float cax = sx[i], cay = syy[i], caz = sz[i];
    float mi = smk[i];

    float df[16], mm_[16];
    float lmax = 0.0f;
    #pragma unroll
    for (int q = 0; q < 16; ++q) {
        int j = q*64 + lane;
        float dx = cax - sx[j];
        float dy = cay - syy[j];
        float dz = caz - sz[j];
        float m2 = mi * smk[j];
        float d = sqrtf(dx*dx + dy*dy + dz*dz + 1e-6f) * m2;
        df[q] = d; mm_[q] = m2;
        lmax = fmaxf(lmax, d);
    }
    #pragma unroll
    for (int o = 32; o > 0; o >>= 1) lmax = fmaxf(lmax, __shfl_xor(lmax, o));

    unsigned long long pack[16];
    #pragma unroll
    for (int q = 0; q < 16; ++q) {
        float da = df[q] + (1.0f - mm_[q]) * lmax;
        pack[q] = ((unsigned long long)__float_as_uint(da) << 32) | (unsigned)(q*64 + lane);
    }

    int   myJw = 0;
    float myDv = 0.0f;
    for (int it = 0; it < KK; ++it) {
        unsigned long long lmin = pack[0];
        #pragma unroll
        for (int q = 1; q < 16; ++q) if (pack[q] < lmin) lmin = pack[q];
        #pragma unroll
        for (int o = 32; o > 0; o >>= 1) {
            unsigned long long other = __shfl_xor(lmin, o);
            if (other < lmin) lmin = other;
        }
        int jw = (int)(lmin & 0xffffffffu);
        if (lane == it) { myJw = jw; myDv = __uint_as_float((unsigned)(lmin >> 32)); }
        int lw = jw & 63, qw = jw >> 6;
        #pragma unroll
        for (int q = 0; q < 16; ++q)
            if (lane == lw && q == qw) pack[q] = ~0ull;
    }
    if (lane < KK) {
        eidx[row*KK + lane]  = myJw;
        dnb [row*KK + lane]  = myDv;
        outEI[row*KK + lane] = (float)myJw;
    }
}

// ---------------------------------------------------------------- phase 2: yedges + edges + nodes
// Union max = nodes (~42.5 KB) -> 3 blocks/CU (was 58.8 KB -> 2/CU): more
// concurrent store-waves to feed the HBM write pole.
union SMem {
    struct { __hip_bfloat16 A[32*KP]; float aj[32][16]; float ai[16]; int didx[32]; } e;
    struct { __hip_bfloat16 A[128*KP2]; float sat[NR][15]; float sfr[NR][9]; } n;
    struct { float sy4[32][4]; float stage[4][16*132]; } y;
};

__global__ __launch_bounds__(256) void k_phase2(
    const float* __restrict__ X, const float* __restrict__ Y,
    const int* __restrict__ Ridx, const int* __restrict__ chain,
    const float* __restrict__ posW, const float* __restrict__ posb,
    const __hip_bfloat16* __restrict__ Bpack,
    const float* __restrict__ lnEg, const float* __restrict__ lnEb,
    const int* __restrict__ eidx, const float* __restrict__ dnb,
    const int* __restrict__ Yt,
    const float* __restrict__ typeW, const float* __restrict__ typeb,
    const int* __restrict__ ptab,
    const __hip_bfloat16* __restrict__ Bpack3, const float* __restrict__ npdb,
    const float* __restrict__ lnNg, const float* __restrict__ lnNb,
    const __hip_bfloat16* __restrict__ Bpack2,
    const float* __restrict__ lnYEg, const float* __restrict__ lnYEb,
    float* __restrict__ outV, float* __restrict__ outE,
    float* __restrict__ outYE)
{
    __shared__ __align__(16) SMem sm;
    // Interleave: even raw -> yedges, odd raw -> edges/nodes (1:1, both 2048+);
    // tail raw>=INTERL -> remaining nodes blocks.
    int raw = blockIdx.x;
    int vb;
    if (raw < INTERL) {
        int pair = raw >> 1;
        vb = (raw & 1) ? (NB_YE + pair) : pair;
    } else {
        vb = (raw - INTERL) + INTERL/2 + NB_YE;   // oth index 2048.. -> vb 4096..
    }
    int tid = threadIdx.x;
    int wv = tid >> 6, lane = tid & 63;
    int col16 = lane & 15, kg = lane >> 4;

    if (vb < NB_YE) {                      // ==== Y_edges ====
        int row = vb;
        if (tid < 32) { sm.y.sy4[tid][0]=0.f; sm.y.sy4[tid][1]=0.f; sm.y.sy4[tid][2]=0.f; sm.y.sy4[tid][3]=0.f; }
        __syncthreads();
        if (tid < MM*3) ((float*)sm.y.sy4)[ (tid/3)*4 + (tid%3) ] = Y[(size_t)row * MM * 3 + tid];

        short8_t bfr[8];
        const short8_t* B2 = (const short8_t*)Bpack2;
        #pragma unroll
        for (int t = 0; t < 8; ++t) bfr[t] = B2[t*64 + lane];
        float g[8], be[8];
        #pragma unroll
        for (int t = 0; t < 8; ++t) { g[t] = lnYEg[t*16 + col16]; be[t] = lnYEb[t*16 + col16]; }
        __syncthreads();

        float* outR = outYE + (size_t)row * 625 * 128;
        float* sbuf = sm.y.stage[wv];
        for (int T = wv; T < 40; T += 4) {
            int p0 = T * 16;
            int p  = p0 + col16;
            int pc = p < 624 ? p : 624;
            int m1 = pc / 25, m2 = pc - 25*m1;
            float dx = sm.y.sy4[m1][0] - sm.y.sy4[m2][0];
            float dy = sm.y.sy4[m1][1] - sm.y.sy4[m2][1];
            float dz = sm.y.sy4[m1][2] - sm.y.sy4[m2][2];
            float d = sqrtf(dx*dx + dy*dy + dz*dz + 1e-6f);
            union { short8_t v; __hip_bfloat16 h[8]; } ua;
            if (kg < 2) {
                #pragma unroll
                for (int j = 0; j < 8; ++j) ua.h[j] = __float2bfloat16(rbf_val(d, kg*8 + j));
            } else {
                ua.v = (short8_t){0,0,0,0,0,0,0,0};
            }
            f32x4 acc[8];
            #pragma unroll
            for (int t = 0; t < 8; ++t)
                acc[t] = __builtin_amdgcn_mfma_f32_16x16x32_bf16(ua.v, bfr[t],
                             (f32x4){0.f,0.f,0.f,0.f}, 0, 0, 0);
            #pragma unroll
            for (int r = 0; r < 4; ++r) {
                float s = 0.0f;
                #pragma unroll
                for (int t = 0; t < 8; ++t) s += acc[t][r];
                s += __shfl_xor(s, 1); s += __shfl_xor(s, 2);
                s += __shfl_xor(s, 4); s += __shfl_xor(s, 8);
                float mean = s * (1.0f/128.0f);
                float q2 = 0.0f;
                #pragma unroll
                for (int t = 0; t < 8; ++t) { float c0 = acc[t][r] - mean; q2 += c0*c0; }
                q2 += __shfl_xor(q2, 1); q2 += __shfl_xor(q2, 2);
                q2 += __shfl_xor(q2, 4); q2 += __shfl_xor(q2, 8);
                float inv = rsqrtf(q2 * (1.0f/128.0f) + 1e-5f);
                float* sr = sbuf + (kg*4 + r) * 132;
                #pragma unroll
                for (int t = 0; t < 8; ++t) sr[t*16 + col16] = (acc[t][r] - mean)*inv*g[t] + be[t];
            }
            #pragma unroll
            for (int it = 0; it < 8; ++it) {
                int off = it*256 + lane*4;
                int rr = (off >> 7), cc = off & 127;
                f32x4 v = *(const f32x4*)(sbuf + rr*132 + cc);
                int gbase = p0*128 + off;
                if (gbase < 80000) __builtin_nontemporal_store(v, (f32x4*)(outR + gbase));
            }
        }
        return;
    }

    if (vb < VB_N) {                       // ==== E (edges), 32 edges = 1 row/block ====
        int r0 = vb - VB_E;                 // residue row
        int b  = r0 >> 10;
        const float* Xb = X + (size_t)b * LLEN * 12;

        if (tid < 32) {
            int e = tid;
            int j = eidx[r0*KK + e];
            const float* xr = Xb + j*12;
            float nx=xr[0], ny=xr[1], nz=xr[2];
            float ax=xr[3], ay=xr[4], az=xr[5];
            float cx=xr[6], cy=xr[7], cz=xr[8];
            float bx=ax-nx, by=ay-ny, bz=az-nz;
            float vx=cx-ax, vy=cy-ay, vz=cz-az;
            float qx = by*vz - bz*vy, qy = bz*vx - bx*vz, qz = bx*vy - by*vx;
            sm.e.aj[e][0]=nx; sm.e.aj[e][1]=ny; sm.e.aj[e][2]=nz;
            sm.e.aj[e][3]=ax; sm.e.aj[e][4]=ay; sm.e.aj[e][5]=az;
            sm.e.aj[e][6]=cx; sm.e.aj[e][7]=cy; sm.e.aj[e][8]=cz;
            sm.e.aj[e][9]=xr[9]; sm.e.aj[e][10]=xr[10]; sm.e.aj[e][11]=xr[11];
            sm.e.aj[e][12] = -0.58273431f*qx + 0.56802827f*bx - 0.54067466f*vx + ax;
            sm.e.aj[e][13] = -0.58273431f*qy + 0.56802827f*by - 0.54067466f*vy + ay;
            sm.e.aj[e][14] = -0.58273431f*qz + 0.56802827f*bz - 0.54067466f*vz + az;
            int off = Ridx[r0] - Ridx[b*LLEN + j];
            int ec = (chain[r0] == chain[b*LLEN + j]) ? 1 : 0;
            int dc = off + 32; dc = dc < 0 ? 0 : (dc > 64 ? 64 : dc);
            sm.e.didx[e] = ec ? dc : 65;
        }
        if (tid == 32) {
            int i = r0 & 1023;
            const float* xr = Xb + i*12;
            float nx=xr[0], ny=xr[1], nz=xr[2];
            float ax=xr[3], ay=xr[4], az=xr[5];
            float cx=xr[6], cy=xr[7], cz=xr[8];
            float bx=ax-nx, by=ay-ny, bz=az-nz;
            float vx=cx-ax, vy=cy-ay, vz=cz-az;
            float qx = by*vz - bz*vy, qy = bz*vx - bx*vz, qz = bx*vy - by*vx;
            sm.e.ai[0]=nx; sm.e.ai[1]=ny; sm.e.ai[2]=nz;
            sm.e.ai[3]=ax; sm.e.ai[4]=ay; sm.e.ai[5]=az;
            sm.e.ai[6]=cx; sm.e.ai[7]=cy; sm.e.ai[8]=cz;
            sm.e.ai[9]=xr[9]; sm.e.ai[10]=xr[10]; sm.e.ai[11]=xr[11];
            sm.e.ai[12] = -0.58273431f*qx + 0.56802827f*bx - 0.54067466f*vx + ax;
            sm.e.ai[13] = -0.58273431f*qy + 0.56802827f*by - 0.54067466f*vy + ay;
            sm.e.ai[14] = -0.58273431f*qz + 0.56802827f*bz - 0.54067466f*vz + az;
        }
        __syncthreads();

        for (int item = tid; item < 32 * 26; item += 256) {
            int e = item / 26, it = item - e * 26;
            union { short8_t v[2]; __hip_bfloat16 h[16]; } uf;
            if (it == 0) {
                int d = sm.e.didx[e];
                #pragma unroll
                for (int c = 0; c < 16; ++c) uf.h[c] = __float2bfloat16(posW[d*16 + c] + posb[c]);
            } else {
                float dist;
                if (it == 1) {
                    dist = dnb[r0*KK + e];
                } else {
                    int p = it - 2;
                    int a = g_PA[p], q = g_PB[p];
                    float dx = sm.e.ai[a*3+0] - sm.e.aj[e][q*3+0];
                    float dy = sm.e.ai[a*3+1] - sm.e.aj[e][q*3+1];
                    float dz = sm.e.ai[a*3+2] - sm.e.aj[e][q*3+2];
                    dist = sqrtf(dx*dx + dy*dy + dz*dz + 1e-6f);
                }
                #pragma unroll
                for (int r = 0; r < 16; ++r) uf.h[r] = __float2bfloat16(rbf_val(dist, r));
            }
            short8_t* dst = (short8_t*)(sm.e.A + e * KP + it * 16);
            dst[0] = uf.v[0];
            dst[1] = uf.v[1];
        }
        __syncthreads();

        int wid = tid >> 6;
        f32x4 acc[8];
        if (wid < 2) {                      // waves 0,1 own tiles 0,1 (16 edges each)
            #pragma unroll
            for (int t = 0; t < 8; ++t) acc[t] = (f32x4){0.f, 0.f, 0.f, 0.f};
            const __hip_bfloat16* Ar = sm.e.A + (wid*16 + col16) * KP + kg * 8;
            const short8_t* Bp = (const short8_t*)Bpack;
            for (int ks = 0; ks < 13; ++ks) {
                short8_t a = *(const short8_t*)(Ar + ks*32);
                #pragma unroll
                for (int t = 0; t < 8; ++t) {
                    short8_t bf = Bp[(ks*8 + t)*64 + lane];
                    acc[t] = __builtin_amdgcn_mfma_f32_16x16x32_bf16(a, bf, acc[t], 0, 0, 0);
                }
            }
        }
        __syncthreads();   // all waves done reading A; safe to reuse as stage

        if (wid < 2) {
            float* sbuf = (float*)sm.e.A + wid * (16*132);
            float g[8], be[8];
            #pragma unroll
            for (int t = 0; t < 8; ++t) { g[t] = lnEg[t*16 + col16]; be[t] = lnEb[t*16 + col16]; }
            #pragma unroll
            for (int r = 0; r < 4; ++r) {
                float s = 0.0f;
                #pragma unroll
                for (int t = 0; t < 8; ++t) s += acc[t][r];
                s += __shfl_xor(s, 1); s += __shfl_xor(s, 2);
                s += __shfl_xor(s, 4); s += __shfl_xor(s, 8);
                float mean = s * (1.0f/128.0f);
                float q2 = 0.0f;
                #pragma unroll
                for (int t = 0; t < 8; ++t) { float c0 = acc[t][r] - mean; q2 += c0*c0; }
                q2 += __shfl_xor(q2, 1); q2 += __shfl_xor(q2, 2);
                q2 += __shfl_xor(q2, 4); q2 += __shfl_xor(q2, 8);
                float inv = rsqrtf(q2 * (1.0f/128.0f) + 1e-5f);
                float* sr = sbuf + (kg*4 + r) * 132;
                #pragma unroll
                for (int t = 0; t < 8; ++t) sr[t*16 + col16] = (acc[t][r] - mean)*inv*g[t] + be[t];
            }
            float* gdst = outE + ((size_t)r0 * KK + wid*16) * 128;
            #pragma unroll
            for (int it = 0; it < 8; ++it) {
                int off = it*256 + lane*4;
                int rr = off >> 7, cc = off & 127;
                f32x4 v = *(const f32x4*)(sbuf + rr*132 + cc);
                __builtin_nontemporal_store(v, (f32x4*)(gdst + off));
            }
        }
        return;
    }

    // ==== V (nodes) ====
    {
        int r0 = (vb - VB_N) * NR;
        int nrows = (2048 - r0) < NR ? (2048 - r0) : NR;
        int natoms = nrows * MM;

        if (tid < nrows) {
            int row = r0 + tid;
            int b = row >> 10, i = row & 1023;
            const float* xr = X + ((size_t)b * LLEN + i) * 12;
            float nx=xr[0], ny=xr[1], nz=xr[2];
            float ax=xr[3], ay=xr[4], az=xr[5];
            float cx=xr[6], cy=xr[7], cz=xr[8];
            float bx=ax-nx, by=ay-ny, bz=az-nz;
            float vx=cx-ax, vy=cy-ay, vz=cz-az;
            float qx = by*vz - bz*vy, qy = bz*vx - bx*vz, qz = bx*vy - by*vx;
            sm.n.sat[tid][0]=nx; sm.n.sat[tid][1]=ny; sm.n.sat[tid][2]=nz;
            sm.n.sat[tid][3]=ax; sm.n.sat[tid][4]=ay; sm.n.sat[tid][5]=az;
            sm.n.sat[tid][6]=cx; sm.n.sat[tid][7]=cy; sm.n.sat[tid][8]=cz;
            sm.n.sat[tid][9]=xr[9]; sm.n.sat[tid][10]=xr[10]; sm.n.sat[tid][11]=xr[11];
            sm.n.sat[tid][12] = -0.58273431f*qx + 0.56802827f*bx - 0.54067466f*vx + ax;
            sm.n.sat[tid][13] = -0.58273431f*qy + 0.56802827f*by - 0.54067466f*vy + ay;
            sm.n.sat[tid][14] = -0.58273431f*qz + 0.56802827f*bz - 0.54067466f*vz + az;
            float e1x = nx-ax, e1y = ny-ay, e1z = nz-az;
            float n1 = fmaxf(sqrtf(e1x*e1x+e1y*e1y+e1z*e1z), 1e-12f);
            e1x/=n1; e1y/=n1; e1z/=n1;
            float dd = e1x*vx + e1y*vy + e1z*vz;
            float u2x = vx - e1x*dd, u2y = vy - e1y*dd, u2z = vz - e1z*dd;
            float n2 = fmaxf(sqrtf(u2x*u2x+u2y*u2y+u2z*u2z), 1e-12f);
            u2x/=n2; u2y/=n2; u2z/=n2;
            sm.n.sfr[tid][0]=e1x; sm.n.sfr[tid][1]=e1y; sm.n.sfr[tid][2]=e1z;
            sm.n.sfr[tid][3]=u2x; sm.n.sfr[tid][4]=u2y; sm.n.sfr[tid][5]=u2z;
            sm.n.sfr[tid][6]=e1y*u2z - e1z*u2y;
            sm.n.sfr[tid][7]=e1z*u2x - e1x*u2z;
            sm.n.sfr[tid][8]=e1x*u2y - e1y*u2x;
        }
        __syncthreads();

        for (int item = tid; item < natoms * 10; item += 256) {
            int a = item / 10, it = item - a * 10;
            int rl = a / MM, m = a - rl * MM;
            int row = r0 + rl;
            const float* Yb = Y + (size_t)row * MM * 3 + m * 3;
            union { short8_t v[2]; __hip_bfloat16 h[16]; } uf;
            if (it < 5) {
                float dx = sm.n.sat[rl][it*3+0] - Yb[0];
                float dy = sm.n.sat[rl][it*3+1] - Yb[1];
                float dz = sm.n.sat[rl][it*3+2] - Yb[2];
                float dist = sqrtf(dx*dx + dy*dy + dz*dz + 1e-6f);
                #pragma unroll
                for (int r = 0; r < 16; ++r) uf.h[r] = __float2bfloat16(rbf_val(dist, r));
            } else if (it < 9) {
                int qq = it - 5;
                int t = Yt[row*MM + m];
                int p1 = ptab[120 + t], p2 = ptab[240 + t];
                #pragma unroll
                for (int c = 0; c < 16; ++c) {
                    int cc = qq*16 + c;
                    uf.h[c] = __float2bfloat16(typeW[t*64 + cc] + typeW[(120+p1)*64 + cc]
                            + typeW[(139+p2)*64 + cc] + typeb[cc]);
                }
            } else {
                float vx = Yb[0] - sm.n.sat[rl][3];
                float vy = Yb[1] - sm.n.sat[rl][4];
                float vz = Yb[2] - sm.n.sat[rl][5];
                float l0 = sm.n.sfr[rl][0]*vx + sm.n.sfr[rl][1]*vy + sm.n.sfr[rl][2]*vz;
                float l1 = sm.n.sfr[rl][3]*vx + sm.n.sfr[rl][4]*vy + sm.n.sfr[rl][5]*vz;
                float l2 = sm.n.sfr[rl][6]*vx + sm.n.sfr[rl][7]*vy + sm.n.sfr[rl][8]*vz;
                float rxy  = sqrtf(l0*l0 + l1*l1 + 1e-8f);
                float rxyz = sqrtf(l0*l0 + l1*l1 + l2*l2) + 1e-8f;
                uf.h[0] = __float2bfloat16(l0 / rxy);
                uf.h[1] = __float2bfloat16(l1 / rxy);
                uf.h[2] = __float2bfloat16(rxy / rxyz);
                uf.h[3] = __float2bfloat16(l2 / rxyz);
                #pragma unroll
                for (int c = 4; c < 16; ++c) uf.h[c] = __float2bfloat16(0.0f);
            }
            short8_t* dst = (short8_t*)(sm.n.A + a * KP2 + it * 16);
            dst[0] = uf.v[0];
            dst[1] = uf.v[1];
        }
        __syncthreads();

        int wid = tid >> 6;
        const short8_t* Bp = (const short8_t*)Bpack3;
        float g[8], be[8], bias[8];
        #pragma unroll
        for (int t = 0; t < 8; ++t) {
            g[t] = lnNg[t*16 + col16]; be[t] = lnNb[t*16 + col16];
            bias[t] = npdb[t*16 + col16];
        }
        #pragma unroll
        for (int half = 0; half < 2; ++half) {
            int tile = wid + half*4;
            int abase = tile * 16;
            if (abase < natoms) {
                const __hip_bfloat16* Ar = sm.n.A + (abase + col16) * KP2 + kg * 8;
                f32x4 acc[8];
                #pragma unroll
                for (int t = 0; t < 8; ++t) acc[t] = (f32x4){0.f, 0.f, 0.f, 0.f};
                for (int ks = 0; ks < 5; ++ks) {
                    short8_t a = *(const short8_t*)(Ar + ks*32);
                    #pragma unroll
                    for (int t = 0; t < 8; ++t) {
                        short8_t bf = Bp[(ks*8 + t)*64 + lane];
                        acc[t] = __builtin_amdgcn_mfma_f32_16x16x32_bf16(a, bf, acc[t], 0, 0, 0);
                    }
                }
                #pragma unroll
                for (int r = 0; r < 4; ++r) {
                    float s = 0.0f;
                    #pragma unroll
                    for (int t = 0; t < 8; ++t) { acc[t][r] += bias[t]; s += acc[t][r]; }
                    s += __shfl_xor(s, 1); s += __shfl_xor(s, 2);
                    s += __shfl_xor(s, 4); s += __shfl_xor(s, 8);
                    float mean = s * (1.0f/128.0f);
                    float q2 = 0.0f;
                    #pragma unroll
                    for (int t = 0; t < 8; ++t) { float c0 = acc[t][r] - mean; q2 += c0*c0; }
                    q2 += __shfl_xor(q2, 1); q2 += __shfl_xor(q2, 2);
                    q2 += __shfl_xor(q2, 4); q2 += __shfl_xor(q2, 8);
                    float inv = rsqrtf(q2 * (1.0f/128.0f) + 1e-5f);
                    int aa = abase + kg*4 + r;
                    if (aa < natoms) {
                        float* dst = outV + ((size_t)r0 * MM + aa) * 128 + col16;
                        #pragma unroll
                        for (int t = 0; t < 8; ++t)
                            __builtin_nontemporal_store((acc[t][r] - mean)*inv*g[t] + be[t], dst + t*16);
                    }
                }
            }
        }
    }
}

// ---------------------------------------------------------------- launcher
extern "C" void kernel_launch(void* const* d_in, const int* in_sizes, int n_in,
                              void* d_out, int out_size, void* d_ws, size_t ws_size,
                              hipStream_t stream) {
    const float* X     = (const float*)d_in[0];
    const float* Y     = (const float*)d_in[1];
    const float* Ym    = (const float*)d_in[2];
    const int*   Yt    = (const int*)d_in[3];
    const float* mask  = (const float*)d_in[4];
    const int*   Ridx  = (const int*)d_in[5];
    const int*   chain = (const int*)d_in[6];
    const float* posW  = (const float*)d_in[7];
    const float* posb  = (const float*)d_in[8];
    const float* edgeW = (const float*)d_in[9];
    const float* lnEg  = (const float*)d_in[10];
    const float* lnEb  = (const float*)d_in[11];
    const float* npdW  = (const float*)d_in[12];
    const float* npdb  = (const float*)d_in[13];
    const float* lnNg  = (const float*)d_in[14];
    const float* lnNb  = (const float*)d_in[15];
    const float* typeW = (const float*)d_in[16];
    const float* typeb = (const float*)d_in[17];
    const float* ynW   = (const float*)d_in[18];
    const float* yeW   = (const float*)d_in[19];
    const float* lnYEg = (const float*)d_in[20];
    const float* lnYEb = (const float*)d_in[21];
    const float* lnYNg = (const float*)d_in[22];
    const float* lnYNb = (const float*)d_in[23];
    const int*   ptab  = (const int*)d_in[24];

    float* o = (float*)d_out;
    bool ws_ok = (ws_size >= (size_t)SCRATCH_BYTES);
    char* scratch = ws_ok ? (char*)d_ws : (char*)(o + OFF_YN);
    int*   eidx = (int*)scratch;
    float* dnb  = (float*)(scratch + BB*LLEN*KK*4);
    __hip_bfloat16* Bpack  = (__hip_bfloat16*)(scratch + 2*BB*LLEN*KK*4);
    __hip_bfloat16* Bpack2 = Bpack + 6656*8;
    __hip_bfloat16* Bpack3 = Bpack2 + 512*8;

    if (ws_ok) {
        k_phase1<<<P1_END, 256, 0, stream>>>(0, X, mask, edgeW, yeW, npdW,
            Bpack, Bpack2, Bpack3, eidx, dnb, o + OFF_EI,
            Yt, Ym, ptab, ynW, lnYNg, lnYNb, o + OFF_YN, o + OFF_YM);
        k_phase2<<<VB_END, 256, 0, stream>>>(
            X, Y, Ridx, chain, posW, posb, Bpack, lnEg, lnEb, eidx, dnb,
            Yt, typeW, typeb, ptab, Bpack3, npdb, lnNg, lnNb,
            Bpack2, lnYEg, lnYEb, o + OFF_V, o + OFF_E, o + OFF_YE);
    } else {
        k_phase1<<<P1_YN, 256, 0, stream>>>(0, X, mask, edgeW, yeW, npdW,
            Bpack, Bpack2, Bpack3, eidx, dnb, o + OFF_EI,
            Yt, Ym, ptab, ynW, lnYNg, lnYNb, o + OFF_YN, o + OFF_YM);
        k_phase2<<<VB_END, 256, 0, stream>>>(
            X, Y, Ridx, chain, posW, posb, Bpack, lnEg, lnEb, eidx, dnb,
            Yt, typeW, typeb, ptab, Bpack3, npdb, lnNg, lnNb,
            Bpack2, lnYEg, lnYEb, o + OFF_V, o + OFF_E, o + OFF_YE);
        k_phase1<<<P1_END - P1_YN, 256, 0, stream>>>(P1_YN, X, mask, edgeW, yeW, npdW,
            Bpack, Bpack2, Bpack3, eidx, dnb, o + OFF_EI,
            Yt, Ym, ptab, ynW, lnYNg, lnYNb, o + OFF_YN, o + OFF_YM);
    }
}

// Round 17
// 197.061 us; speedup vs baseline: 1.1511x; 1.1511x over previous
//
#include <hip/hip_runtime.h>
#include <hip/hip_bf16.h>
#include <stdint.h>

#define BB 2
#define LLEN 1024
#define MM 25
#define KK 32

// d_out is FLOAT32, concatenated in return order:
// (V, E, E_idx, Y_nodes, Y_edges, Y_m) — offsets in f32 elements.
#define OFF_V   0
#define OFF_E   6553600
#define OFF_EI  14942208
#define OFF_YN  15007744
#define OFF_YE  21561344
#define OFF_YM  185401344

#define KP 424          // edge A-tile row stride (bf16)
#define KP2 168         // node A-tile row stride (bf16)
#define NR 5            // rows per nodes block

// phase-1 virtual blocks: [0,512) topk | [512,550) prep | [550,13350) ynodes
#define P1_PREP 512
#define P1_YN   550
#define P1_END  (P1_YN + BB*LLEN*MM/4)   // 13350
// phase-2 virtual blocks: [0,2048) yedges | [2048,3072) edges | [3072,3482) nodes
#define NB_YE  (BB*LLEN)                      // 2048
#define VB_E   NB_YE
#define VB_N   (VB_E + BB*LLEN/2)             // 3072
#define VB_END (VB_N + (BB*LLEN+NR-1)/NR)     // 3482
#define NB_OTH (VB_END - NB_YE)               // 1434 (edges+nodes)
#define INTERL (2*NB_OTH)                     // 2868

#define SCRATCH_BYTES (680*1024)

typedef __attribute__((ext_vector_type(8))) short short8_t;
typedef __attribute__((ext_vector_type(4))) float f32x4;

__constant__ int g_PA[24] = {0,2,3,4,1,1,1,1,0,0,0,4,4,3,0,2,3,4,2,3,4,2,3,2};
__constant__ int g_PB[24] = {0,2,3,4,0,2,3,4,2,3,4,2,3,2,1,1,1,1,0,0,0,4,4,3};

__device__ __forceinline__ float rbf_val(float d, int r) {
    float mu = 2.0f + (20.0f / 15.0f) * (float)r;
    float z = (d - mu) * 0.8f;
    return __expf(-z * z);
}

// ------------------------------------------------- phase 1: topk + prep + ynodes
__global__ __launch_bounds__(256) void k_phase1(
    int vbase,
    const float* __restrict__ X, const float* __restrict__ mask,
    const float* __restrict__ W, const float* __restrict__ yeW,
    const float* __restrict__ npdW,
    __hip_bfloat16* __restrict__ Bp, __hip_bfloat16* __restrict__ Bp2,
    __hip_bfloat16* __restrict__ Bp3,
    int* __restrict__ eidx, float* __restrict__ dnb,
    float* __restrict__ outEI,
    const int* __restrict__ Yt, const float* __restrict__ Ym,
    const int* __restrict__ ptab, const float* __restrict__ ynW,
    const float* __restrict__ lnYNg, const float* __restrict__ lnYNb,
    float* __restrict__ outYN, float* __restrict__ outYM)
{
    __shared__ float sx[1024], syy[1024], sz[1024], smk[1024];
    int vb = blockIdx.x + vbase;
    int tid = threadIdx.x;
    int wid = tid >> 6, lane = tid & 63;

    if (vb >= P1_YN) {                    // ---- ynodes (light, input-only deps)
        int row = (vb - P1_YN) * 4 + wid;
        int t = Yt[row];
        int p1 = ptab[120 + t], p2 = ptab[240 + t];
        int r0 = t, r1 = 120 + p1, r2 = 139 + p2;
        float x0 = ynW[r0*128 + lane] + ynW[r1*128 + lane] + ynW[r2*128 + lane];
        float x1 = ynW[r0*128 + 64 + lane] + ynW[r1*128 + 64 + lane] + ynW[r2*128 + 64 + lane];
        float s = x0 + x1, s2 = x0*x0 + x1*x1;
        #pragma unroll
        for (int o = 1; o < 64; o <<= 1) { s += __shfl_xor(s, o); s2 += __shfl_xor(s2, o); }
        float mean = s * (1.0f/128.0f);
        float var  = s2 * (1.0f/128.0f) - mean*mean;
        float inv  = rsqrtf(var + 1e-5f);
        size_t base = (size_t)row * 128;
        outYN[base + lane]      = (x0 - mean)*inv*lnYNg[lane]    + lnYNb[lane];
        outYN[base + 64 + lane] = (x1 - mean)*inv*lnYNg[64+lane] + lnYNb[64+lane];
        if (lane == 0) outYM[row] = Ym[row];
        return;
    }

    if (vb >= P1_PREP) {                  // ---- B-pack prep
        int idx = (vb - P1_PREP) * 256 + tid;
        if (idx < 6656) {
            int ln = idx & 63, tt = (idx >> 6) & 7, ks = idx >> 9;
            int k0 = ks*32 + (ln >> 4)*8;
            int n  = tt*16 + (ln & 15);
            __hip_bfloat16* dst = Bp + (size_t)idx * 8;
            #pragma unroll
            for (int j = 0; j < 8; ++j) dst[j] = __float2bfloat16(W[(size_t)(k0 + j)*128 + n]);
        } else if (idx < 7168) {
            int i2 = idx - 6656;
            int ln = i2 & 63, tt = i2 >> 6;
            int kg = ln >> 4;
            int n  = tt*16 + (ln & 15);
            __hip_bfloat16* dst = Bp2 + (size_t)i2 * 8;
            #pragma unroll
            for (int j = 0; j < 8; ++j) {
                float v = (kg < 2) ? yeW[(size_t)(kg*8 + j)*128 + n] : 0.0f;
                dst[j] = __float2bfloat16(v);
            }
        } else if (idx < 9728) {
            int i3 = idx - 7168;
            int ln = i3 & 63, tt = (i3 >> 6) & 7, ks = i3 >> 9;
            int k0 = ks*32 + (ln >> 4)*8;
            int n  = tt*16 + (ln & 15);
            __hip_bfloat16* dst = Bp3 + (size_t)i3 * 8;
            #pragma unroll
            for (int j = 0; j < 8; ++j) {
                int k = k0 + j;
                float v = (k < 148) ? npdW[(size_t)k*128 + n] : 0.0f;
                dst[j] = __float2bfloat16(v);
            }
        }
        return;
    }

    // ---- top-k (validated wave tournament, LDS-staged coords)
    int row0 = vb * 4;
    int b = row0 >> 10;
    const float* Xb = X + (size_t)b * LLEN * 12;
    const float* mb = mask + b * LLEN;
    for (int j = tid; j < 1024; j += 256) {
        sx[j]  = Xb[j*12+3];
        syy[j] = Xb[j*12+4];
        sz[j]  = Xb[j*12+5];
        smk[j] = mb[j];
    }
    __syncthreads();

    int row = row0 + wid, i = row & 1023;
    float cax = sx[i], cay = syy[i], caz = sz[i];
    float mi = smk[i];

    float df[16], mm_[16];
    float lmax = 0.0f;
    #pragma unroll
    for (int q = 0; q < 16; ++q) {
        int j = q*64 + lane;
        float dx = cax - sx[j];
        float dy = cay - syy[j];
        float dz = caz - sz[j];
        float m2 = mi * smk[j];
        float d = sqrtf(dx*dx + dy*dy + dz*dz + 1e-6f) * m2;
        df[q] = d; mm_[q] = m2;
        lmax = fmaxf(lmax, d);
    }
    #pragma unroll
    for (int o = 32; o > 0; o >>= 1) lmax = fmaxf(lmax, __shfl_xor(lmax, o));

    unsigned long long pack[16];
    #pragma unroll
    for (int q = 0; q < 16; ++q) {
        float da = df[q] + (1.0f - mm_[q]) * lmax;
        pack[q] = ((unsigned long long)__float_as_uint(da) << 32) | (unsigned)(q*64 + lane);
    }

    int   myJw = 0;
    float myDv = 0.0f;
    for (int it = 0; it < KK; ++it) {
        unsigned long long lmin = pack[0];
        #pragma unroll
        for (int q = 1; q < 16; ++q) if (pack[q] < lmin) lmin = pack[q];
        #pragma unroll
        for (int o = 32; o > 0; o >>= 1) {
            unsigned long long other = __shfl_xor(lmin, o);
            if (other < lmin) lmin = other;
        }
        int jw = (int)(lmin & 0xffffffffu);
        if (lane == it) { myJw = jw; myDv = __uint_as_float((unsigned)(lmin >> 32)); }
        int lw = jw & 63, qw = jw >> 6;
        #pragma unroll
        for (int q = 0; q < 16; ++q)
            if (lane == lw && q == qw) pack[q] = ~0ull;
    }
    if (lane < KK) {
        eidx[row*KK + lane]  = myJw;
        dnb [row*KK + lane]  = myDv;
        outEI[row*KK + lane] = (float)myJw;
    }
}

// ---------------------------------------------------------------- phase 2: yedges + edges + nodes
union SMem {
    struct { __hip_bfloat16 A[64*KP]; float aj[64][16]; float ai[2][16]; int didx[64]; } e;
    struct { __hip_bfloat16 A[128*KP2]; float sat[NR][15]; float sfr[NR][9]; } n;
    struct { float sy4[32][4]; float stage[4][16*132]; } y;
};

__global__ __launch_bounds__(256) void k_phase2(
    const float* __restrict__ X, const float* __restrict__ Y,
    const int* __restrict__ Ridx, const int* __restrict__ chain,
    const float* __restrict__ posW, const float* __restrict__ posb,
    const __hip_bfloat16* __restrict__ Bpack,
    const float* __restrict__ lnEg, const float* __restrict__ lnEb,
    const int* __restrict__ eidx, const float* __restrict__ dnb,
    const int* __restrict__ Yt,
    const float* __restrict__ typeW, const float* __restrict__ typeb,
    const int* __restrict__ ptab,
    const __hip_bfloat16* __restrict__ Bpack3, const float* __restrict__ npdb,
    const float* __restrict__ lnNg, const float* __restrict__ lnNb,
    const __hip_bfloat16* __restrict__ Bpack2,
    const float* __restrict__ lnYEg, const float* __restrict__ lnYEb,
    float* __restrict__ outV, float* __restrict__ outE,
    float* __restrict__ outYE)
{
    __shared__ __align__(16) SMem sm;
    // Interleave dispatch order: even raw -> yedges (write-bound), odd raw ->
    // edges/nodes (compute-bound). NT stores on all outputs keep L2 clean for
    // the per-block Bpack re-reads.
    int raw = blockIdx.x;
    int vb;
    if (raw < INTERL) {
        int pair = raw >> 1;
        vb = (raw & 1) ? (NB_YE + pair) : pair;
    } else {
        vb = (raw - INTERL) + NB_OTH;       // yedges NB_OTH..2047
    }
    int tid = threadIdx.x;
    int wv = tid >> 6, lane = tid & 63;
    int col16 = lane & 15, kg = lane >> 4;

    if (vb < NB_YE) {                      // ==== Y_edges ====
        int row = vb;
        if (tid < 32) { sm.y.sy4[tid][0]=0.f; sm.y.sy4[tid][1]=0.f; sm.y.sy4[tid][2]=0.f; sm.y.sy4[tid][3]=0.f; }
        __syncthreads();
        if (tid < MM*3) ((float*)sm.y.sy4)[ (tid/3)*4 + (tid%3) ] = Y[(size_t)row * MM * 3 + tid];

        short8_t bfr[8];
        const short8_t* B2 = (const short8_t*)Bpack2;
        #pragma unroll
        for (int t = 0; t < 8; ++t) bfr[t] = B2[t*64 + lane];
        float g[8], be[8];
        #pragma unroll
        for (int t = 0; t < 8; ++t) { g[t] = lnYEg[t*16 + col16]; be[t] = lnYEb[t*16 + col16]; }
        __syncthreads();

        float* outR = outYE + (size_t)row * 625 * 128;
        float* sbuf = sm.y.stage[wv];
        for (int T = wv; T < 40; T += 4) {
            int p0 = T * 16;
            int p  = p0 + col16;
            int pc = p < 624 ? p : 624;
            int m1 = pc / 25, m2 = pc - 25*m1;
            float dx = sm.y.sy4[m1][0] - sm.y.sy4[m2][0];
            float dy = sm.y.sy4[m1][1] - sm.y.sy4[m2][1];
            float dz = sm.y.sy4[m1][2] - sm.y.sy4[m2][2];
            float d = sqrtf(dx*dx + dy*dy + dz*dz + 1e-6f);
            union { short8_t v; __hip_bfloat16 h[8]; } ua;
            if (kg < 2) {
                #pragma unroll
                for (int j = 0; j < 8; ++j) ua.h[j] = __float2bfloat16(rbf_val(d, kg*8 + j));
            } else {
                ua.v = (short8_t){0,0,0,0,0,0,0,0};
            }
            f32x4 acc[8];
            #pragma unroll
            for (int t = 0; t < 8; ++t)
                acc[t] = __builtin_amdgcn_mfma_f32_16x16x32_bf16(ua.v, bfr[t],
                             (f32x4){0.f,0.f,0.f,0.f}, 0, 0, 0);
            #pragma unroll
            for (int r = 0; r < 4; ++r) {
                float s = 0.0f;
                #pragma unroll
                for (int t = 0; t < 8; ++t) s += acc[t][r];
                s += __shfl_xor(s, 1); s += __shfl_xor(s, 2);
                s += __shfl_xor(s, 4); s += __shfl_xor(s, 8);
                float mean = s * (1.0f/128.0f);
                float q2 = 0.0f;
                #pragma unroll
                for (int t = 0; t < 8; ++t) { float c0 = acc[t][r] - mean; q2 += c0*c0; }
                q2 += __shfl_xor(q2, 1); q2 += __shfl_xor(q2, 2);
                q2 += __shfl_xor(q2, 4); q2 += __shfl_xor(q2, 8);
                float inv = rsqrtf(q2 * (1.0f/128.0f) + 1e-5f);
                float* sr = sbuf + (kg*4 + r) * 132;
                #pragma unroll
                for (int t = 0; t < 8; ++t) sr[t*16 + col16] = (acc[t][r] - mean)*inv*g[t] + be[t];
            }
            #pragma unroll
            for (int it = 0; it < 8; ++it) {
                int off = it*256 + lane*4;
                int rr = (off >> 7), cc = off & 127;
                f32x4 v = *(const f32x4*)(sbuf + rr*132 + cc);
                int gbase = p0*128 + off;
                if (gbase < 80000) __builtin_nontemporal_store(v, (f32x4*)(outR + gbase));
            }
        }
        return;
    }

    if (vb < VB_N) {                       // ==== E (edges) ====
        int r0 = (vb - VB_E) * 2;
        int b  = r0 >> 10;
        const float* Xb = X + (size_t)b * LLEN * 12;

        if (tid < 64) {
            int e = tid, row = r0 + (e >> 5), k = e & 31;
            int j = eidx[row*KK + k];
            const float* xr = Xb + j*12;
            float nx=xr[0], ny=xr[1], nz=xr[2];
            float ax=xr[3], ay=xr[4], az=xr[5];
            float cx=xr[6], cy=xr[7], cz=xr[8];
            float bx=ax-nx, by=ay-ny, bz=az-nz;
            float vx=cx-ax, vy=cy-ay, vz=cz-az;
            float qx = by*vz - bz*vy, qy = bz*vx - bx*vz, qz = bx*vy - by*vx;
            sm.e.aj[e][0]=nx; sm.e.aj[e][1]=ny; sm.e.aj[e][2]=nz;
            sm.e.aj[e][3]=ax; sm.e.aj[e][4]=ay; sm.e.aj[e][5]=az;
            sm.e.aj[e][6]=cx; sm.e.aj[e][7]=cy; sm.e.aj[e][8]=cz;
            sm.e.aj[e][9]=xr[9]; sm.e.aj[e][10]=xr[10]; sm.e.aj[e][11]=xr[11];
            sm.e.aj[e][12] = -0.58273431f*qx + 0.56802827f*bx - 0.54067466f*vx + ax;
            sm.e.aj[e][13] = -0.58273431f*qy + 0.56802827f*by - 0.54067466f*vy + ay;
            sm.e.aj[e][14] = -0.58273431f*qz + 0.56802827f*bz - 0.54067466f*vz + az;
            int off = Ridx[row] - Ridx[b*LLEN + j];
            int ec = (chain[row] == chain[b*LLEN + j]) ? 1 : 0;
            int dc = off + 32; dc = dc < 0 ? 0 : (dc > 64 ? 64 : dc);
            sm.e.didx[e] = ec ? dc : 65;
        }
        if (tid >= 64 && tid < 66) {
            int rl = tid - 64;
            int i = (r0 + rl) & 1023;
            const float* xr = Xb + i*12;
            float nx=xr[0], ny=xr[1], nz=xr[2];
            float ax=xr[3], ay=xr[4], az=xr[5];
            float cx=xr[6], cy=xr[7], cz=xr[8];
            float bx=ax-nx, by=ay-ny, bz=az-nz;
            float vx=cx-ax, vy=cy-ay, vz=cz-az;
            float qx = by*vz - bz*vy, qy = bz*vx - bx*vz, qz = bx*vy - by*vx;
            sm.e.ai[rl][0]=nx; sm.e.ai[rl][1]=ny; sm.e.ai[rl][2]=nz;
            sm.e.ai[rl][3]=ax; sm.e.ai[rl][4]=ay; sm.e.ai[rl][5]=az;
            sm.e.ai[rl][6]=cx; sm.e.ai[rl][7]=cy; sm.e.ai[rl][8]=cz;
            sm.e.ai[rl][9]=xr[9]; sm.e.ai[rl][10]=xr[10]; sm.e.ai[rl][11]=xr[11];
            sm.e.ai[rl][12] = -0.58273431f*qx + 0.56802827f*bx - 0.54067466f*vx + ax;
            sm.e.ai[rl][13] = -0.58273431f*qy + 0.56802827f*by - 0.54067466f*vy + ay;
            sm.e.ai[rl][14] = -0.58273431f*qz + 0.56802827f*bz - 0.54067466f*vz + az;
        }
        __syncthreads();

        for (int item = tid; item < 64 * 26; item += 256) {
            int e = item / 26, it = item - e * 26;
            int rl = e >> 5;
            union { short8_t v[2]; __hip_bfloat16 h[16]; } uf;
            if (it == 0) {
                int d = sm.e.didx[e];
                #pragma unroll
                for (int c = 0; c < 16; ++c) uf.h[c] = __float2bfloat16(posW[d*16 + c] + posb[c]);
            } else {
                float dist;
                if (it == 1) {
                    dist = dnb[(r0 + rl)*KK + (e & 31)];
                } else {
                    int p = it - 2;
                    int a = g_PA[p], q = g_PB[p];
                    float dx = sm.e.ai[rl][a*3+0] - sm.e.aj[e][q*3+0];
                    float dy = sm.e.ai[rl][a*3+1] - sm.e.aj[e][q*3+1];
                    float dz = sm.e.ai[rl][a*3+2] - sm.e.aj[e][q*3+2];
                    dist = sqrtf(dx*dx + dy*dy + dz*dz + 1e-6f);
                }
                #pragma unroll
                for (int r = 0; r < 16; ++r) uf.h[r] = __float2bfloat16(rbf_val(dist, r));
            }
            short8_t* dst = (short8_t*)(sm.e.A + e * KP + it * 16);
            dst[0] = uf.v[0];
            dst[1] = uf.v[1];
        }
        __syncthreads();

        int wid = tid >> 6;
        f32x4 acc[8];
        #pragma unroll
        for (int t = 0; t < 8; ++t) acc[t] = (f32x4){0.f, 0.f, 0.f, 0.f};
        const __hip_bfloat16* Ar = sm.e.A + (wid*16 + col16) * KP + kg * 8;
        const short8_t* Bp = (const short8_t*)Bpack;
        for (int ks = 0; ks < 13; ++ks) {
            short8_t a = *(const short8_t*)(Ar + ks*32);
            #pragma unroll
            for (int t = 0; t < 8; ++t) {
                short8_t bf = Bp[(ks*8 + t)*64 + lane];
                acc[t] = __builtin_amdgcn_mfma_f32_16x16x32_bf16(a, bf, acc[t], 0, 0, 0);
            }
        }
        __syncthreads();

        float* sbuf = (float*)sm.e.A + wid * (16*132);
        float g[8], be[8];
        #pragma unroll
        for (int t = 0; t < 8; ++t) { g[t] = lnEg[t*16 + col16]; be[t] = lnEb[t*16 + col16]; }
        #pragma unroll
        for (int r = 0; r < 4; ++r) {
            float s = 0.0f;
            #pragma unroll
            for (int t = 0; t < 8; ++t) s += acc[t][r];
            s += __shfl_xor(s, 1); s += __shfl_xor(s, 2);
            s += __shfl_xor(s, 4); s += __shfl_xor(s, 8);
            float mean = s * (1.0f/128.0f);
            float q2 = 0.0f;
            #pragma unroll
            for (int t = 0; t < 8; ++t) { float c0 = acc[t][r] - mean; q2 += c0*c0; }
            q2 += __shfl_xor(q2, 1); q2 += __shfl_xor(q2, 2);
            q2 += __shfl_xor(q2, 4); q2 += __shfl_xor(q2, 8);
            float inv = rsqrtf(q2 * (1.0f/128.0f) + 1e-5f);
            float* sr = sbuf + (kg*4 + r) * 132;
            #pragma unroll
            for (int t = 0; t < 8; ++t) sr[t*16 + col16] = (acc[t][r] - mean)*inv*g[t] + be[t];
        }
        float* gdst = outE + ((size_t)r0 * KK + wid*16) * 128;
        #pragma unroll
        for (int it = 0; it < 8; ++it) {
            int off = it*256 + lane*4;
            int rr = off >> 7, cc = off & 127;
            f32x4 v = *(const f32x4*)(sbuf + rr*132 + cc);
            __builtin_nontemporal_store(v, (f32x4*)(gdst + off));
        }
        return;
    }

    // ==== V (nodes) ====
    {
        int r0 = (vb - VB_N) * NR;
        int nrows = (2048 - r0) < NR ? (2048 - r0) : NR;
        int natoms = nrows * MM;

        if (tid < nrows) {
            int row = r0 + tid;
            int b = row >> 10, i = row & 1023;
            const float* xr = X + ((size_t)b * LLEN + i) * 12;
            float nx=xr[0], ny=xr[1], nz=xr[2];
            float ax=xr[3], ay=xr[4], az=xr[5];
            float cx=xr[6], cy=xr[7], cz=xr[8];
            float bx=ax-nx, by=ay-ny, bz=az-nz;
            float vx=cx-ax, vy=cy-ay, vz=cz-az;
            float qx = by*vz - bz*vy, qy = bz*vx - bx*vz, qz = bx*vy - by*vx;
            sm.n.sat[tid][0]=nx; sm.n.sat[tid][1]=ny; sm.n.sat[tid][2]=nz;
            sm.n.sat[tid][3]=ax; sm.n.sat[tid][4]=ay; sm.n.sat[tid][5]=az;
            sm.n.sat[tid][6]=cx; sm.n.sat[tid][7]=cy; sm.n.sat[tid][8]=cz;
            sm.n.sat[tid][9]=xr[9]; sm.n.sat[tid][10]=xr[10]; sm.n.sat[tid][11]=xr[11];
            sm.n.sat[tid][12] = -0.58273431f*qx + 0.56802827f*bx - 0.54067466f*vx + ax;
            sm.n.sat[tid][13] = -0.58273431f*qy + 0.56802827f*by - 0.54067466f*vy + ay;
            sm.n.sat[tid][14] = -0.58273431f*qz + 0.56802827f*bz - 0.54067466f*vz + az;
            float e1x = nx-ax, e1y = ny-ay, e1z = nz-az;
            float n1 = fmaxf(sqrtf(e1x*e1x+e1y*e1y+e1z*e1z), 1e-12f);
            e1x/=n1; e1y/=n1; e1z/=n1;
            float dd = e1x*vx + e1y*vy + e1z*vz;
            float u2x = vx - e1x*dd, u2y = vy - e1y*dd, u2z = vz - e1z*dd;
            float n2 = fmaxf(sqrtf(u2x*u2x+u2y*u2y+u2z*u2z), 1e-12f);
            u2x/=n2; u2y/=n2; u2z/=n2;
            sm.n.sfr[tid][0]=e1x; sm.n.sfr[tid][1]=e1y; sm.n.sfr[tid][2]=e1z;
            sm.n.sfr[tid][3]=u2x; sm.n.sfr[tid][4]=u2y; sm.n.sfr[tid][5]=u2z;
            sm.n.sfr[tid][6]=e1y*u2z - e1z*u2y;
            sm.n.sfr[tid][7]=e1z*u2x - e1x*u2z;
            sm.n.sfr[tid][8]=e1x*u2y - e1y*u2x;
        }
        __syncthreads();

        for (int item = tid; item < natoms * 10; item += 256) {
            int a = item / 10, it = item - a * 10;
            int rl = a / MM, m = a - rl * MM;
            int row = r0 + rl;
            const float* Yb = Y + (size_t)row * MM * 3 + m * 3;
            union { short8_t v[2]; __hip_bfloat16 h[16]; } uf;
            if (it < 5) {
                float dx = sm.n.sat[rl][it*3+0] - Yb[0];
                float dy = sm.n.sat[rl][it*3+1] - Yb[1];
                float dz = sm.n.sat[rl][it*3+2] - Yb[2];
                float dist = sqrtf(dx*dx + dy*dy + dz*dz + 1e-6f);
                #pragma unroll
                for (int r = 0; r < 16; ++r) uf.h[r] = __float2bfloat16(rbf_val(dist, r));
            } else if (it < 9) {
                int qq = it - 5;
                int t = Yt[row*MM + m];
                int p1 = ptab[120 + t], p2 = ptab[240 + t];
                #pragma unroll
                for (int c = 0; c < 16; ++c) {
                    int cc = qq*16 + c;
                    uf.h[c] = __float2bfloat16(typeW[t*64 + cc] + typeW[(120+p1)*64 + cc]
                            + typeW[(139+p2)*64 + cc] + typeb[cc]);
                }
            } else {
                float vx = Yb[0] - sm.n.sat[rl][3];
                float vy = Yb[1] - sm.n.sat[rl][4];
                float vz = Yb[2] - sm.n.sat[rl][5];
                float l0 = sm.n.sfr[rl][0]*vx + sm.n.sfr[rl][1]*vy + sm.n.sfr[rl][2]*vz;
                float l1 = sm.n.sfr[rl][3]*vx + sm.n.sfr[rl][4]*vy + sm.n.sfr[rl][5]*vz;
                float l2 = sm.n.sfr[rl][6]*vx + sm.n.sfr[rl][7]*vy + sm.n.sfr[rl][8]*vz;
                float rxy  = sqrtf(l0*l0 + l1*l1 + 1e-8f);
                float rxyz = sqrtf(l0*l0 + l1*l1 + l2*l2) + 1e-8f;
                uf.h[0] = __float2bfloat16(l0 / rxy);
                uf.h[1] = __float2bfloat16(l1 / rxy);
                uf.h[2] = __float2bfloat16(rxy / rxyz);
                uf.h[3] = __float2bfloat16(l2 / rxyz);
                #pragma unroll
                for (int c = 4; c < 16; ++c) uf.h[c] = __float2bfloat16(0.0f);
            }
            short8_t* dst = (short8_t*)(sm.n.A + a * KP2 + it * 16);
            dst[0] = uf.v[0];
            dst[1] = uf.v[1];
        }
        __syncthreads();

        int wid = tid >> 6;
        const short8_t* Bp = (const short8_t*)Bpack3;
        float g[8], be[8], bias[8];
        #pragma unroll
        for (int t = 0; t < 8; ++t) {
            g[t] = lnNg[t*16 + col16]; be[t] = lnNb[t*16 + col16];
            bias[t] = npdb[t*16 + col16];
        }
        #pragma unroll
        for (int half = 0; half < 2; ++half) {
            int tile = wid + half*4;
            int abase = tile * 16;
            if (abase < natoms) {
                const __hip_bfloat16* Ar = sm.n.A + (abase + col16) * KP2 + kg * 8;
                f32x4 acc[8];
                #pragma unroll
                for (int t = 0; t < 8; ++t) acc[t] = (f32x4){0.f, 0.f, 0.f, 0.f};
                for (int ks = 0; ks < 5; ++ks) {
                    short8_t a = *(const short8_t*)(Ar + ks*32);
                    #pragma unroll
                    for (int t = 0; t < 8; ++t) {
                        short8_t bf = Bp[(ks*8 + t)*64 + lane];
                        acc[t] = __builtin_amdgcn_mfma_f32_16x16x32_bf16(a, bf, acc[t], 0, 0, 0);
                    }
                }
                #pragma unroll
                for (int r = 0; r < 4; ++r) {
                    float s = 0.0f;
                    #pragma unroll
                    for (int t = 0; t < 8; ++t) { acc[t][r] += bias[t]; s += acc[t][r]; }
                    s += __shfl_xor(s, 1); s += __shfl_xor(s, 2);
                    s += __shfl_xor(s, 4); s += __shfl_xor(s, 8);
                    float mean = s * (1.0f/128.0f);
                    float q2 = 0.0f;
                    #pragma unroll
                    for (int t = 0; t < 8; ++t) { float c0 = acc[t][r] - mean; q2 += c0*c0; }
                    q2 += __shfl_xor(q2, 1); q2 += __shfl_xor(q2, 2);
                    q2 += __shfl_xor(q2, 4); q2 += __shfl_xor(q2, 8);
                    float inv = rsqrtf(q2 * (1.0f/128.0f) + 1e-5f);
                    int aa = abase + kg*4 + r;
                    if (aa < natoms) {
                        float* dst = outV + ((size_t)r0 * MM + aa) * 128 + col16;
                        #pragma unroll
                        for (int t = 0; t < 8; ++t)
                            __builtin_nontemporal_store((acc[t][r] - mean)*inv*g[t] + be[t], dst + t*16);
                    }
                }
            }
        }
    }
}

// ---------------------------------------------------------------- launcher
extern "C" void kernel_launch(void* const* d_in, const int* in_sizes, int n_in,
                              void* d_out, int out_size, void* d_ws, size_t ws_size,
                              hipStream_t stream) {
    const float* X     = (const float*)d_in[0];
    const float* Y     = (const float*)d_in[1];
    const float* Ym    = (const float*)d_in[2];
    const int*   Yt    = (const int*)d_in[3];
    const float* mask  = (const float*)d_in[4];
    const int*   Ridx  = (const int*)d_in[5];
    const int*   chain = (const int*)d_in[6];
    const float* posW  = (const float*)d_in[7];
    const float* posb  = (const float*)d_in[8];
    const float* edgeW = (const float*)d_in[9];
    const float* lnEg  = (const float*)d_in[10];
    const float* lnEb  = (const float*)d_in[11];
    const float* npdW  = (const float*)d_in[12];
    const float* npdb  = (const float*)d_in[13];
    const float* lnNg  = (const float*)d_in[14];
    const float* lnNb  = (const float*)d_in[15];
    const float* typeW = (const float*)d_in[16];
    const float* typeb = (const float*)d_in[17];
    const float* ynW   = (const float*)d_in[18];
    const float* yeW   = (const float*)d_in[19];
    const float* lnYEg = (const float*)d_in[20];
    const float* lnYEb = (const float*)d_in[21];
    const float* lnYNg = (const float*)d_in[22];
    const float* lnYNb = (const float*)d_in[23];
    const int*   ptab  = (const int*)d_in[24];

    float* o = (float*)d_out;
    bool ws_ok = (ws_size >= (size_t)SCRATCH_BYTES);
    char* scratch = ws_ok ? (char*)d_ws : (char*)(o + OFF_YN);
    int*   eidx = (int*)scratch;
    float* dnb  = (float*)(scratch + BB*LLEN*KK*4);
    __hip_bfloat16* Bpack  = (__hip_bfloat16*)(scratch + 2*BB*LLEN*KK*4);
    __hip_bfloat16* Bpack2 = Bpack + 6656*8;
    __hip_bfloat16* Bpack3 = Bpack2 + 512*8;

    if (ws_ok) {
        k_phase1<<<P1_END, 256, 0, stream>>>(0, X, mask, edgeW, yeW, npdW,
            Bpack, Bpack2, Bpack3, eidx, dnb, o + OFF_EI,
            Yt, Ym, ptab, ynW, lnYNg, lnYNb, o + OFF_YN, o + OFF_YM);
        k_phase2<<<VB_END, 256, 0, stream>>>(
            X, Y, Ridx, chain, posW, posb, Bpack, lnEg, lnEb, eidx, dnb,
            Yt, typeW, typeb, ptab, Bpack3, npdb, lnNg, lnNb,
            Bpack2, lnYEg, lnYEb, o + OFF_V, o + OFF_E, o + OFF_YE);
    } else {
        k_phase1<<<P1_YN, 256, 0, stream>>>(0, X, mask, edgeW, yeW, npdW,
            Bpack, Bpack2, Bpack3, eidx, dnb, o + OFF_EI,
            Yt, Ym, ptab, ynW, lnYNg, lnYNb, o + OFF_YN, o + OFF_YM);
        k_phase2<<<VB_END, 256, 0, stream>>>(
            X, Y, Ridx, chain, posW, posb, Bpack, lnEg, lnEb, eidx, dnb,
            Yt, typeW, typeb, ptab, Bpack3, npdb, lnNg, lnNb,
            Bpack2, lnYEg, lnYEb, o + OFF_V, o + OFF_E, o + OFF_YE);
        k_phase1<<<P1_END - P1_YN, 256, 0, stream>>>(P1_YN, X, mask, edgeW, yeW, npdW,
            Bpack, Bpack2, Bpack3, eidx, dnb, o + OFF_EI,
            Yt, Ym, ptab, ynW, lnYNg, lnYNb, o + OFF_YN, o + OFF_YM);
    }
}